// Round 1
// baseline (127.185 us; speedup 1.0000x reference)
//
#include <hip/hip_runtime.h>
#include <math.h>

#define Bn 32
#define An 3
#define Hn 128
#define Wn 128
#define Cn 80
#define Nn 50

// Weights / denominators (match reference means exactly)
#define TOT_XY  ((float)(Bn)*(An)*(Hn)*(Wn)*2.0f)   // 3,145,728
#define TOT_CF  ((float)(Bn)*(An)*(Hn)*(Wn))        // 1,572,864
#define TOT_CL  (TOT_CF*(float)(Cn))                // 125,829,120

__global__ __launch_bounds__(256) void yolo_loss_kernel(
    const float* __restrict__ out_xy,
    const float* __restrict__ out_wh,
    const float* __restrict__ out_conf,
    const float* __restrict__ out_class,
    const float* __restrict__ target,
    float* __restrict__ d_out)
{
    const float W12 = 5.0f / TOT_XY;          // xy and wh terms (per squared element)
    const float W3  = 1.0f / TOT_CF;          // obj conf
    const float W4  = 0.5f / TOT_CF;          // noobj conf
    const float W5  = 1.0f / TOT_CL;          // bce per element
    const float base_e = -log1pf(1e-9f);      // bce value at p=0,y=0 (non-obj cells)

    __shared__ double s_red[256];
    double acc = 0.0;
    const int tid = threadIdx.x;

    if (blockIdx.x < Bn) {
        // ---------- per-image sparse path ----------
        const int b = blockIdx.x;
        __shared__ int   s_gx[Nn], s_gy[Nn], s_anchor[Nn], s_vraw[Nn];
        __shared__ float s_iou[Nn][An];
        __shared__ float s_txy[Nn][2], s_twh[Nn][2];
        __shared__ int   s_tcls[Nn];
        // dedup'd cell list (last-write-wins like XLA CPU scatter order)
        __shared__ int   s_ncell;
        __shared__ int   s_cc[Nn];
        __shared__ float s_ciou[Nn][An];
        __shared__ int   s_obj[Nn][An];
        __shared__ float s_ctxy[Nn][An][2], s_ctwh[Nn][An][2];
        __shared__ int   s_ctcls[Nn][An];

        if (tid < Nn) {
            const int n = tid;
            const float* t = target + ((size_t)b * Nn + n) * 5;
            const float tx = t[0], ty = t[1], tw = t[2], th = t[3];
            s_vraw[n] = (tx >= 0.0f) ? 1 : 0;
            // jnp.round == round-half-even == rintf (default rounding mode)
            int gx = (int)rintf(tx * (float)Wn - 0.5f);
            gx = min(max(gx, 0), Wn - 1);
            int gy = (int)rintf(ty * (float)Hn - 0.5f);
            gy = min(max(gy, 0), Hn - 1);
            s_gx[n] = gx; s_gy[n] = gy;
            s_txy[n][0] = tx; s_txy[n][1] = ty;
            s_twh[n][0] = tw; s_twh[n][1] = th;
            s_tcls[n] = (int)t[4];

            float best = -1e30f; int anc = 0;
            #pragma unroll
            for (int a = 0; a < An; ++a) {
                const size_t wbase = (((size_t)(b * An + a) * Hn + gy) * Wn + gx) * 2;
                const float pw0 = out_wh[wbase + 0];
                const float pw1 = out_wh[wbase + 1];
                const float inter = fminf(tw, pw0) * fminf(th, pw1);
                const float uni   = tw * th + pw0 * pw1 - inter;
                const float iou   = inter / (uni + 1e-9f);
                s_iou[n][a] = iou;
                if (iou > best) { best = iou; anc = a; }   // first max wins (argmax)
            }
            s_anchor[n] = anc;
        }
        __syncthreads();

        if (tid == 0) {
            int nc = 0;
            for (int n = 0; n < Nn; ++n) {
                if (!s_vraw[n]) break;                 // cumprod-valid: once 0, all later 0
                const int cc = s_gy[n] * Wn + s_gx[n];
                int i;
                for (i = 0; i < nc; ++i) if (s_cc[i] == cc) break;
                if (i == nc) {
                    s_cc[nc] = cc;
                    s_obj[nc][0] = s_obj[nc][1] = s_obj[nc][2] = 0;
                    ++nc;
                }
                // mask_conf: set for ALL anchors (last writer per cell wins)
                #pragma unroll
                for (int a = 0; a < An; ++a) s_ciou[i][a] = s_iou[n][a];
                // mask_xy/wh/class: set at (anchor, cell) (last writer wins)
                const int a = s_anchor[n];
                s_obj[i][a] = 1;
                s_ctxy[i][a][0] = s_txy[n][0]; s_ctxy[i][a][1] = s_txy[n][1];
                s_ctwh[i][a][0] = s_twh[n][0]; s_ctwh[i][a][1] = s_twh[n][1];
                s_ctcls[i][a] = s_tcls[n];
            }
            s_ncell = nc;
        }
        __syncthreads();

        const int total = s_ncell * An;
        for (int i = tid; i < total; i += blockDim.x) {
            const int ci = i / An, a = i - ci * An;
            const int cc = s_cc[ci];
            const int gy = cc / Wn, gx = cc - gy * Wn;
            const size_t base = ((size_t)(b * An + a) * Hn + gy) * Wn + gx;

            const float conf = out_conf[base];
            const float mc   = s_ciou[ci][a];
            const int   obj  = s_obj[ci][a] && (s_ctwh[ci][a][0] > 0.0f);
            const float d    = conf - mc;
            // replace baseline 0.5*conf^2 with (obj?1:0.5)*(conf-iou)^2
            acc += (double)((obj ? W3 : W4) * d * d) - (double)(W4 * conf * conf);

            if (obj) {
                const float ex0 = out_xy[base * 2 + 0] - s_ctxy[ci][a][0];
                const float ex1 = out_xy[base * 2 + 1] - s_ctxy[ci][a][1];
                const float sw0 = sqrtf(out_wh[base * 2 + 0]) - sqrtf(s_ctwh[ci][a][0]);
                const float sw1 = sqrtf(out_wh[base * 2 + 1]) - sqrtf(s_ctwh[ci][a][1]);
                acc += (double)(W12 * (ex0 * ex0 + ex1 * ex1));
                acc += (double)(W12 * (sw0 * sw0 + sw1 * sw1));

                const int tc = s_ctcls[ci][a];
                const float* cls = out_class + base * (size_t)Cn;
                float bsum = 0.0f;
                for (int c = 0; c < Cn; ++c) {
                    const float p = cls[c];
                    const float term = (c == tc)
                        ? -fmaxf(logf(p + 1e-9f), -100.0f)
                        : -fmaxf(log1pf(-p + 1e-9f), -100.0f);
                    bsum += term - base_e;   // correction vs non-obj baseline
                }
                acc += (double)(W5 * bsum);
            }
        }
        // add global constants once: bce baseline mean = base_e
        if (blockIdx.x == 0 && tid == 0) acc += (double)base_e;
    } else {
        // ---------- dense baseline: 0.5/total * sum(conf^2) ----------
        const int sb = blockIdx.x - Bn;
        const int nSumBlocks = gridDim.x - Bn;
        const float4* cf4 = (const float4*)out_conf;
        const int n4 = (Bn * An * Hn * Wn) / 4;
        float partial = 0.0f;
        for (int i = sb * blockDim.x + tid; i < n4; i += nSumBlocks * blockDim.x) {
            const float4 v = cf4[i];
            partial += v.x * v.x + v.y * v.y + v.z * v.z + v.w * v.w;
        }
        acc = (double)partial * (double)W4;
    }

    // block reduce (double) then one float atomic per block
    s_red[tid] = acc;
    __syncthreads();
    for (int s = 128; s > 0; s >>= 1) {
        if (tid < s) s_red[tid] += s_red[tid + s];
        __syncthreads();
    }
    if (tid == 0) atomicAdd(d_out, (float)s_red[0]);
}

extern "C" void kernel_launch(void* const* d_in, const int* in_sizes, int n_in,
                              void* d_out, int out_size, void* d_ws, size_t ws_size,
                              hipStream_t stream) {
    const float* out_xy    = (const float*)d_in[0];
    const float* out_wh    = (const float*)d_in[1];
    const float* out_conf  = (const float*)d_in[2];
    const float* out_class = (const float*)d_in[3];
    const float* target    = (const float*)d_in[4];
    float* out = (float*)d_out;

    // d_out is poisoned before timing and accumulated via atomics -> zero it every call
    hipMemsetAsync(out, 0, sizeof(float), stream);

    const int nblocks = Bn + 480;   // 32 sparse blocks + 480 conf^2 reduction blocks
    yolo_loss_kernel<<<nblocks, 256, 0, stream>>>(out_xy, out_wh, out_conf,
                                                  out_class, target, out);
}

// Round 2
// 125.397 us; speedup vs baseline: 1.0143x; 1.0143x over previous
//
#include <hip/hip_runtime.h>
#include <math.h>

#define Bn 32
#define An 3
#define Hn 128
#define Wn 128
#define Cn 80
#define Nn 50

#define NBLK 512          // 32 sparse blocks + 480 dense-sum blocks

// Weights / denominators (match reference means exactly)
#define TOT_XY  ((float)(Bn)*(An)*(Hn)*(Wn)*2.0f)   // 3,145,728
#define TOT_CF  ((float)(Bn)*(An)*(Hn)*(Wn))        // 1,572,864
#define TOT_CL  (TOT_CF*(float)(Cn))                // 125,829,120

__global__ __launch_bounds__(256) void yolo_partial_kernel(
    const float* __restrict__ out_xy,
    const float* __restrict__ out_wh,
    const float* __restrict__ out_conf,
    const float* __restrict__ out_class,
    const float* __restrict__ target,
    double* __restrict__ partials)
{
    const float W12 = 5.0f / TOT_XY;          // xy and wh terms (per squared element)
    const float W3  = 1.0f / TOT_CF;          // obj conf
    const float W4  = 0.5f / TOT_CF;          // noobj conf
    const float W5  = 1.0f / TOT_CL;          // bce per element
    const float base_e = -log1pf(1e-9f);      // bce value at p=0,y=0 (non-obj cells)

    __shared__ double s_red[256];
    double acc = 0.0;
    const int tid = threadIdx.x;

    if (blockIdx.x < Bn) {
        // ---------- per-image sparse path ----------
        const int b = blockIdx.x;
        __shared__ int   s_gx[Nn], s_gy[Nn], s_anchor[Nn], s_vraw[Nn];
        __shared__ float s_iou[Nn][An];
        __shared__ float s_txy[Nn][2], s_twh[Nn][2];
        __shared__ int   s_tcls[Nn];
        // dedup'd cell list (last-write-wins scatter order)
        __shared__ int   s_ncell;
        __shared__ int   s_cc[Nn];
        __shared__ float s_ciou[Nn][An];
        __shared__ int   s_obj[Nn][An];
        __shared__ float s_ctxy[Nn][An][2], s_ctwh[Nn][An][2];
        __shared__ int   s_ctcls[Nn][An];

        if (tid < Nn) {
            const int n = tid;
            const float* t = target + ((size_t)b * Nn + n) * 5;
            const float tx = t[0], ty = t[1], tw = t[2], th = t[3];
            s_vraw[n] = (tx >= 0.0f) ? 1 : 0;
            // jnp.round == round-half-even == rintf (default rounding mode)
            int gx = (int)rintf(tx * (float)Wn - 0.5f);
            gx = min(max(gx, 0), Wn - 1);
            int gy = (int)rintf(ty * (float)Hn - 0.5f);
            gy = min(max(gy, 0), Hn - 1);
            s_gx[n] = gx; s_gy[n] = gy;
            s_txy[n][0] = tx; s_txy[n][1] = ty;
            s_twh[n][0] = tw; s_twh[n][1] = th;
            s_tcls[n] = (int)t[4];

            float best = -1e30f; int anc = 0;
            #pragma unroll
            for (int a = 0; a < An; ++a) {
                const size_t wbase = (((size_t)(b * An + a) * Hn + gy) * Wn + gx) * 2;
                const float pw0 = out_wh[wbase + 0];
                const float pw1 = out_wh[wbase + 1];
                const float inter = fminf(tw, pw0) * fminf(th, pw1);
                const float uni   = tw * th + pw0 * pw1 - inter;
                const float iou   = inter / (uni + 1e-9f);
                s_iou[n][a] = iou;
                if (iou > best) { best = iou; anc = a; }   // first max wins (argmax)
            }
            s_anchor[n] = anc;
        }
        __syncthreads();

        if (tid == 0) {
            int nc = 0;
            for (int n = 0; n < Nn; ++n) {
                if (!s_vraw[n]) break;                 // cumprod-valid: once 0, all later 0
                const int cc = s_gy[n] * Wn + s_gx[n];
                int i;
                for (i = 0; i < nc; ++i) if (s_cc[i] == cc) break;
                if (i == nc) {
                    s_cc[nc] = cc;
                    s_obj[nc][0] = s_obj[nc][1] = s_obj[nc][2] = 0;
                    ++nc;
                }
                // mask_conf: set for ALL anchors (last writer per cell wins)
                #pragma unroll
                for (int a = 0; a < An; ++a) s_ciou[i][a] = s_iou[n][a];
                // mask_xy/wh/class: set at (anchor, cell) (last writer wins)
                const int a = s_anchor[n];
                s_obj[i][a] = 1;
                s_ctxy[i][a][0] = s_txy[n][0]; s_ctxy[i][a][1] = s_txy[n][1];
                s_ctwh[i][a][0] = s_twh[n][0]; s_ctwh[i][a][1] = s_twh[n][1];
                s_ctcls[i][a] = s_tcls[n];
            }
            s_ncell = nc;
        }
        __syncthreads();

        const int total = s_ncell * An;
        for (int i = tid; i < total; i += blockDim.x) {
            const int ci = i / An, a = i - ci * An;
            const int cc = s_cc[ci];
            const int gy = cc / Wn, gx = cc - gy * Wn;
            const size_t base = ((size_t)(b * An + a) * Hn + gy) * Wn + gx;

            const float conf = out_conf[base];
            const float mc   = s_ciou[ci][a];
            const int   obj  = s_obj[ci][a] && (s_ctwh[ci][a][0] > 0.0f);
            const float d    = conf - mc;
            // replace baseline 0.5*conf^2 with (obj?1:0.5)*(conf-iou)^2
            acc += (double)((obj ? W3 : W4) * d * d) - (double)(W4 * conf * conf);

            if (obj) {
                const float ex0 = out_xy[base * 2 + 0] - s_ctxy[ci][a][0];
                const float ex1 = out_xy[base * 2 + 1] - s_ctxy[ci][a][1];
                const float sw0 = sqrtf(out_wh[base * 2 + 0]) - sqrtf(s_ctwh[ci][a][0]);
                const float sw1 = sqrtf(out_wh[base * 2 + 1]) - sqrtf(s_ctwh[ci][a][1]);
                acc += (double)(W12 * (ex0 * ex0 + ex1 * ex1));
                acc += (double)(W12 * (sw0 * sw0 + sw1 * sw1));

                const int tc = s_ctcls[ci][a];
                const float* cls = out_class + base * (size_t)Cn;
                float bsum = 0.0f;
                for (int c = 0; c < Cn; ++c) {
                    const float p = cls[c];
                    const float term = (c == tc)
                        ? -fmaxf(logf(p + 1e-9f), -100.0f)
                        : -fmaxf(log1pf(-p + 1e-9f), -100.0f);
                    bsum += term - base_e;   // correction vs non-obj baseline
                }
                acc += (double)(W5 * bsum);
            }
        }
    } else {
        // ---------- dense baseline: 0.5/total * sum(conf^2) ----------
        const int sb = blockIdx.x - Bn;
        const int nSumBlocks = NBLK - Bn;
        const float4* cf4 = (const float4*)out_conf;
        const int n4 = (Bn * An * Hn * Wn) / 4;
        float partial = 0.0f;
        for (int i = sb * blockDim.x + tid; i < n4; i += nSumBlocks * blockDim.x) {
            const float4 v = cf4[i];
            partial += v.x * v.x + v.y * v.y + v.z * v.z + v.w * v.w;
        }
        acc = (double)partial * (double)W4;
    }

    // block reduce (double), one partial per block (all NBLK slots written every call)
    s_red[tid] = acc;
    __syncthreads();
    for (int s = 128; s > 0; s >>= 1) {
        if (tid < s) s_red[tid] += s_red[tid + s];
        __syncthreads();
    }
    if (tid == 0) partials[blockIdx.x] = s_red[0];
}

__global__ __launch_bounds__(256) void yolo_final_kernel(
    const double* __restrict__ partials, float* __restrict__ d_out)
{
    const float base_e = -log1pf(1e-9f);
    __shared__ double s_red[256];
    const int tid = threadIdx.x;
    double acc = partials[tid] + partials[tid + 256];   // NBLK = 512
    s_red[tid] = acc;
    __syncthreads();
    for (int s = 128; s > 0; s >>= 1) {
        if (tid < s) s_red[tid] += s_red[tid + s];
        __syncthreads();
    }
    if (tid == 0) d_out[0] = (float)(s_red[0] + (double)base_e);
}

extern "C" void kernel_launch(void* const* d_in, const int* in_sizes, int n_in,
                              void* d_out, int out_size, void* d_ws, size_t ws_size,
                              hipStream_t stream) {
    const float* out_xy    = (const float*)d_in[0];
    const float* out_wh    = (const float*)d_in[1];
    const float* out_conf  = (const float*)d_in[2];
    const float* out_class = (const float*)d_in[3];
    const float* target    = (const float*)d_in[4];
    double* partials = (double*)d_ws;   // NBLK doubles, fully rewritten every call
    float* out = (float*)d_out;

    yolo_partial_kernel<<<NBLK, 256, 0, stream>>>(out_xy, out_wh, out_conf,
                                                  out_class, target, partials);
    yolo_final_kernel<<<1, 256, 0, stream>>>(partials, out);
}

// Round 3
// 29.357 us; speedup vs baseline: 4.3323x; 4.2714x over previous
//
#include <hip/hip_runtime.h>
#include <math.h>

#define Bn 32
#define An 3
#define Hn 128
#define Wn 128
#define Cn 80
#define Nn 50

#define NBLK 512          // 32 sparse blocks + 480 dense-sum blocks

// Weights / denominators (match reference means exactly)
#define TOT_XY  ((float)(Bn)*(An)*(Hn)*(Wn)*2.0f)   // 3,145,728
#define TOT_CF  ((float)(Bn)*(An)*(Hn)*(Wn))        // 1,572,864
#define TOT_CL  (TOT_CF*(float)(Cn))                // 125,829,120

__global__ __launch_bounds__(256) void yolo_partial_kernel(
    const float* __restrict__ out_xy,
    const float* __restrict__ out_wh,
    const float* __restrict__ out_conf,
    const float* __restrict__ out_class,
    const float* __restrict__ target,
    double* __restrict__ partials)
{
    const float W12 = 5.0f / TOT_XY;          // xy and wh terms (per squared element)
    const float W3  = 1.0f / TOT_CF;          // obj conf
    const float W4  = 0.5f / TOT_CF;          // noobj conf
    const float W5  = 1.0f / TOT_CL;          // bce per element
    const float base_e = -log1pf(1e-9f);      // bce value at p=0,y=0 (non-obj cells)

    __shared__ double s_red[256];
    double acc = 0.0;
    const int tid = threadIdx.x;

    if (blockIdx.x < Bn) {
        // ---------- per-image sparse path (fully parallel, no serial dedup) ----------
        const int b = blockIdx.x;
        __shared__ int   s_vraw[Nn], s_valid[Nn];
        __shared__ int   s_cell[Nn], s_anchor[Nn];
        __shared__ float s_iou[Nn][An];
        __shared__ float s_txy[Nn][2], s_twh[Nn][2];
        __shared__ int   s_tcls[Nn];
        __shared__ int   s_confw[Nn];          // n owns mask_conf row of its cell
        __shared__ int   s_ancw[Nn];           // n owns mask_xy/wh/class at (cell,anchor)
        __shared__ int   s_obja[Nn][An];       // (cell[n],a) is an obj location

        // Phase 1: decode targets, gather pred wh, compute iou + argmax anchor
        if (tid < Nn) {
            const int n = tid;
            const float* t = target + ((size_t)b * Nn + n) * 5;
            const float tx = t[0], ty = t[1], tw = t[2], th = t[3];
            s_vraw[n] = (tx >= 0.0f) ? 1 : 0;
            // jnp.round == round-half-even == rintf (default rounding mode)
            int gx = (int)rintf(tx * (float)Wn - 0.5f);
            gx = min(max(gx, 0), Wn - 1);
            int gy = (int)rintf(ty * (float)Hn - 0.5f);
            gy = min(max(gy, 0), Hn - 1);
            s_cell[n] = gy * Wn + gx;
            s_txy[n][0] = tx; s_txy[n][1] = ty;
            s_twh[n][0] = tw; s_twh[n][1] = th;
            s_tcls[n] = (int)t[4];

            float best = -1e30f; int anc = 0;
            #pragma unroll
            for (int a = 0; a < An; ++a) {
                const size_t wbase = (((size_t)(b * An + a) * Hn + gy) * Wn + gx) * 2;
                const float pw0 = out_wh[wbase + 0];
                const float pw1 = out_wh[wbase + 1];
                const float inter = fminf(tw, pw0) * fminf(th, pw1);
                const float uni   = tw * th + pw0 * pw1 - inter;
                const float iou   = inter / (uni + 1e-9f);
                s_iou[n][a] = iou;
                if (iou > best) { best = iou; anc = a; }   // first max wins (argmax)
            }
            s_anchor[n] = anc;
        }
        __syncthreads();

        // Phase 2: cumprod validity + winner flags (each thread scans all Nn; parallel)
        if (tid < Nn) {
            const int n = tid;
            int v = 1;
            for (int m = 0; m <= n; ++m) v &= s_vraw[m];   // cumprod(t_x >= 0)
            s_valid[n] = v;
        }
        __syncthreads();
        if (tid < Nn) {
            const int n = tid;
            const int cell_n = s_cell[n];
            const int anc_n  = s_anchor[n];
            int cw = s_valid[n], aw = s_valid[n];
            int obj0 = 0, obj1 = 0, obj2 = 0;
            for (int m = 0; m < Nn; ++m) {
                if (!s_valid[m] || s_cell[m] != cell_n) continue;
                const int am = s_anchor[m];
                const int o = (s_twh[m][0] > 0.0f) ? 1 : 0;  // last writer's tw decides
                if (am == 0) obj0 = o; else if (am == 1) obj1 = o; else obj2 = o;
                if (m > n) {
                    cw = 0;
                    if (am == anc_n) aw = 0;
                }
            }
            s_confw[n] = cw;
            s_ancw[n]  = aw;
            s_obja[n][0] = obj0; s_obja[n][1] = obj1; s_obja[n][2] = obj2;
        }
        __syncthreads();

        // Phase 3: conf corrections — one item per (conf-winner cell, anchor)
        if (tid < Nn * An) {
            const int n = tid / An, a = tid - n * An;
            if (s_confw[n]) {
                const int cc = s_cell[n];
                const int gy = cc / Wn, gx = cc - gy * Wn;
                const size_t base = ((size_t)(b * An + a) * Hn + gy) * Wn + gx;
                const float conf = out_conf[base];
                const float d    = conf - s_iou[n][a];
                const float w    = s_obja[n][a] ? W3 : W4;
                // replace baseline 0.5*conf^2 with (obj?1:0.5)*(conf-iou)^2
                acc += (double)(w * d * d) - (double)(W4 * conf * conf);
            }
        }

        // Phase 4a: xy/wh corrections — one item per anchor-winner
        if (tid < Nn) {
            const int n = tid;
            if (s_ancw[n] && s_twh[n][0] > 0.0f) {
                const int cc = s_cell[n];
                const int gy = cc / Wn, gx = cc - gy * Wn;
                const size_t base = ((size_t)(b * An + s_anchor[n]) * Hn + gy) * Wn + gx;
                const float ex0 = out_xy[base * 2 + 0] - s_txy[n][0];
                const float ex1 = out_xy[base * 2 + 1] - s_txy[n][1];
                const float sw0 = sqrtf(out_wh[base * 2 + 0]) - sqrtf(s_twh[n][0]);
                const float sw1 = sqrtf(out_wh[base * 2 + 1]) - sqrtf(s_twh[n][1]);
                acc += (double)(W12 * (ex0 * ex0 + ex1 * ex1));
                acc += (double)(W12 * (sw0 * sw0 + sw1 * sw1));
            }
        }

        // Phase 4b: BCE corrections — items (n, c) over Nn*Cn = 4000, strided
        for (int i = tid; i < Nn * Cn; i += blockDim.x) {
            const int n = i / Cn, c = i - n * Cn;
            if (s_ancw[n] && s_twh[n][0] > 0.0f) {
                const int cc = s_cell[n];
                const int gy = cc / Wn, gx = cc - gy * Wn;
                const size_t base = ((size_t)(b * An + s_anchor[n]) * Hn + gy) * Wn + gx;
                const float p = out_class[base * (size_t)Cn + c];
                const float term = (c == s_tcls[n])
                    ? -fmaxf(logf(p + 1e-9f), -100.0f)
                    : -fmaxf(log1pf(-p + 1e-9f), -100.0f);
                acc += (double)(W5 * (term - base_e));   // correction vs non-obj baseline
            }
        }
    } else {
        // ---------- dense baseline: 0.5/total * sum(conf^2) ----------
        const int sb = blockIdx.x - Bn;
        const int nSumBlocks = NBLK - Bn;
        const float4* cf4 = (const float4*)out_conf;
        const int n4 = (Bn * An * Hn * Wn) / 4;
        float partial = 0.0f;
        for (int i = sb * blockDim.x + tid; i < n4; i += nSumBlocks * blockDim.x) {
            const float4 v = cf4[i];
            partial += v.x * v.x + v.y * v.y + v.z * v.z + v.w * v.w;
        }
        acc = (double)partial * (double)W4;
    }

    // block reduce (double), one partial per block (all NBLK slots written every call)
    s_red[tid] = acc;
    __syncthreads();
    for (int s = 128; s > 0; s >>= 1) {
        if (tid < s) s_red[tid] += s_red[tid + s];
        __syncthreads();
    }
    if (tid == 0) partials[blockIdx.x] = s_red[0];
}

__global__ __launch_bounds__(256) void yolo_final_kernel(
    const double* __restrict__ partials, float* __restrict__ d_out)
{
    const float base_e = -log1pf(1e-9f);
    __shared__ double s_red[256];
    const int tid = threadIdx.x;
    double acc = partials[tid] + partials[tid + 256];   // NBLK = 512
    s_red[tid] = acc;
    __syncthreads();
    for (int s = 128; s > 0; s >>= 1) {
        if (tid < s) s_red[tid] += s_red[tid + s];
        __syncthreads();
    }
    if (tid == 0) d_out[0] = (float)(s_red[0] + (double)base_e);
}

extern "C" void kernel_launch(void* const* d_in, const int* in_sizes, int n_in,
                              void* d_out, int out_size, void* d_ws, size_t ws_size,
                              hipStream_t stream) {
    const float* out_xy    = (const float*)d_in[0];
    const float* out_wh    = (const float*)d_in[1];
    const float* out_conf  = (const float*)d_in[2];
    const float* out_class = (const float*)d_in[3];
    const float* target    = (const float*)d_in[4];
    double* partials = (double*)d_ws;   // NBLK doubles, fully rewritten every call
    float* out = (float*)d_out;

    yolo_partial_kernel<<<NBLK, 256, 0, stream>>>(out_xy, out_wh, out_conf,
                                                  out_class, target, partials);
    yolo_final_kernel<<<1, 256, 0, stream>>>(partials, out);
}